// Round 15
// baseline (47.183 us; speedup 1.0000x reference)
//
#include <hip/hip_runtime.h>

#define Nn 512
#define Dd 128
#define Kk 2048
#define Cc 100
#define NPAIR 8         // block pairs: kc = pr and pr + 8
#define KCW 64          // stats granularity: 64 wave-chunks of 32 cols
#define G  8            // samples per pass
#define SQROW 164       // padded q-row stride in LDS floats
constexpr float INV_T = 1.0f / 0.07f;

// ws layout (floats):
// [0, 32768)         stats_m[n*KCW+kcw]
// [32768, 65536)     stats_s[n*KCW+kcw]
// [65536, 66048)     per-sample loss

// Compute + reduce all samples of one pass against one V tile (R10's proven body)
__device__ __forceinline__ void compute_item(
    const float* __restrict__ sq, const float4 (&V)[16],
    const int* __restrict__ s_list, int g0, int gs,
    int dg, int l, int kcw,
    float* __restrict__ stats_m, float* __restrict__ stats_s)
{
    #pragma unroll
    for (int s = 0; s < G; ++s) {
        if (s >= gs) break;              // block-uniform

        const float* srow = sq + s * SQROW + 20 * dg;
        const float4 qa = *reinterpret_cast<const float4*>(srow + 0);
        const float4 qb = *reinterpret_cast<const float4*>(srow + 4);
        const float4 qc = *reinterpret_cast<const float4*>(srow + 8);
        const float4 qd = *reinterpret_cast<const float4*>(srow + 12);
        const float qq[16] = {qa.x, qa.y, qa.z, qa.w, qb.x, qb.y, qb.z, qb.w,
                              qc.x, qc.y, qc.z, qc.w, qd.x, qd.y, qd.z, qd.w};

        float4 a = make_float4(0.f, 0.f, 0.f, 0.f);
        #pragma unroll
        for (int j = 0; j < 16; ++j) {
            a.x = fmaf(qq[j], V[j].x, a.x);
            a.y = fmaf(qq[j], V[j].y, a.y);
            a.z = fmaf(qq[j], V[j].z, a.z);
            a.w = fmaf(qq[j], V[j].w, a.w);
        }

        // d-reduce across dg (lane bits 3..5)
        #pragma unroll
        for (int mask = 8; mask <= 32; mask <<= 1) {
            a.x += __shfl_xor(a.x, mask, 64);
            a.y += __shfl_xor(a.y, mask, 64);
            a.z += __shfl_xor(a.z, mask, 64);
            a.w += __shfl_xor(a.w, mask, 64);
        }
        const float lx = a.x * INV_T, ly = a.y * INV_T;
        const float lz = a.z * INV_T, lw = a.w * INV_T;

        // softmax stats across c4 (lane bits 0..2)
        float mv = fmaxf(fmaxf(lx, ly), fmaxf(lz, lw));
        #pragma unroll
        for (int mask = 1; mask <= 4; mask <<= 1)
            mv = fmaxf(mv, __shfl_xor(mv, mask, 64));
        float ev = expf(lx - mv) + expf(ly - mv) + expf(lz - mv) + expf(lw - mv);
        #pragma unroll
        for (int mask = 1; mask <= 4; mask <<= 1)
            ev += __shfl_xor(ev, mask, 64);

        if (l == 0) {
            const int n = s_list[g0 + s];
            stats_m[(size_t)n * KCW + kcw] = mv;
            stats_s[(size_t)n * KCW + kcw] = ev;
        }
    }
}

__global__ __launch_bounds__(256) void chunk_kernel(
    const float* __restrict__ q,
    const float* __restrict__ queue, const int* __restrict__ labels,
    float* __restrict__ ws)
{
    const int c  = blockIdx.x >> 3;      // class
    const int pr = blockIdx.x & 7;       // pair: items kc = pr, pr + 8
    const int t  = threadIdx.x;
    const int w  = t >> 6;               // wave 0..3 -> 32-col sub-chunk
    const int l  = t & 63;               // lane
    const int dg = l >> 3;               // d-group 0..7 (16 rows each)
    const int c4 = l & 7;                // col-group 0..7 (4 cols each)

    __shared__ int   s_list[Nn];
    __shared__ int   s_cnt;
    __shared__ float sq[G * SQROW];      // padded staged q rows, 5.25 KB

    // 1) prefetch all 8 label words first (ballot waits only on these)
    int lab[8];
    #pragma unroll
    for (int r = 0; r < 8; ++r) lab[r] = labels[l + r * 64];

    // 2) issue item-0's 16 V loads
    const float* slab = queue + (size_t)c * Dd * Kk
                      + (size_t)(dg * 16) * Kk + w * 32 + c4 * 4;
    float4 V0[16];
    #pragma unroll
    for (int j = 0; j < 16; ++j)
        V0[j] = *reinterpret_cast<const float4*>(slab + pr * 128 + (size_t)j * Kk);

    // 3) ballot scan from registers (wave 0)
    if (t < 64) {
        int cnt = 0;
        #pragma unroll
        for (int r = 0; r < 8; ++r) {
            unsigned long long m = __ballot(lab[r] == c);
            if (lab[r] == c) {
                int pos = __popcll(m & ((1ull << l) - 1ull));
                s_list[cnt + pos] = r * 64 + l;
            }
            cnt += __popcll(m);
        }
        if (l == 0) s_cnt = cnt;
    }
    __syncthreads();
    const int cnt = s_cnt;
    if (cnt == 0) return;                 // block-uniform (rare)

    float* stats_m = ws;
    float* stats_s = ws + (size_t)Nn * KCW;
    const int kcw0 = pr * 4 + w;
    const int kcw1 = (pr + 8) * 4 + w;

    float4 V1[16];

    for (int g0 = 0; g0 < cnt; g0 += G) {
        const int gs = min(G, cnt - g0);

        // stage q rows padded (idx(d) = d + 4*(d>>4)): shared by both items.
        // NOTE: issued BEFORE V1 so the stage's vmcnt drain covers only V0.
        {
            const int s = t >> 5;        // sample 0..7
            const int f = t & 31;        // float4 chunk
            const int d = 4 * f;
            float4 v = make_float4(0.f, 0.f, 0.f, 0.f);
            if (s < gs)
                v = *reinterpret_cast<const float4*>(q + (size_t)s_list[g0 + s] * Dd + d);
            *reinterpret_cast<float4*>(&sq[s * SQROW + d + 4 * (d >> 4)]) = v;
        }
        __syncthreads();

        // 4) first pass only: issue item-1's 16 V loads NOW -> they are in
        //    flight during item-0's entire compute (compiler uses counted
        //    vmcnt waits for V0 uses since V1 is newer in the queue).
        if (g0 == 0) {
            #pragma unroll
            for (int j = 0; j < 16; ++j)
                V1[j] = *reinterpret_cast<const float4*>(slab + (pr + 8) * 128 + (size_t)j * Kk);
        }

        // item 0: compute from V0 while V1 is landing
        compute_item(sq, V0, s_list, g0, gs, dg, l, kcw0, stats_m, stats_s);
        // item 1: same samples, same staged sq, V1 (landed under item-0 compute)
        compute_item(sq, V1, s_list, g0, gs, dg, l, kcw1, stats_m, stats_s);

        __syncthreads();
    }
}

__global__ __launch_bounds__(64) void loss_kernel(
    const float* __restrict__ q, const float* __restrict__ k,
    const float* __restrict__ ws, float* __restrict__ loss)
{
    const int n = blockIdx.x * 64 + threadIdx.x;
    const float* stats_m = ws;
    const float* stats_s = ws + (size_t)Nn * KCW;

    // l_pos = dot(q[n], k[n]) / T
    float lp = 0.f;
    const float4* qv = reinterpret_cast<const float4*>(q + (size_t)n * Dd);
    const float4* kv = reinterpret_cast<const float4*>(k + (size_t)n * Dd);
    #pragma unroll
    for (int j = 0; j < Dd / 4; ++j) {
        float4 a = qv[j], b = kv[j];
        lp = fmaf(a.x, b.x, lp); lp = fmaf(a.y, b.y, lp);
        lp = fmaf(a.z, b.z, lp); lp = fmaf(a.w, b.w, lp);
    }
    lp *= INV_T;

    const float4* mmv = reinterpret_cast<const float4*>(stats_m + (size_t)n * KCW);
    const float4* ssv = reinterpret_cast<const float4*>(stats_s + (size_t)n * KCW);

    float m = lp;
    #pragma unroll
    for (int j = 0; j < KCW / 4; ++j) {
        float4 a = mmv[j];
        m = fmaxf(m, fmaxf(fmaxf(a.x, a.y), fmaxf(a.z, a.w)));
    }
    float sum = expf(lp - m);
    #pragma unroll
    for (int j = 0; j < KCW / 4; ++j) {
        float4 a = mmv[j], b = ssv[j];
        sum += b.x * expf(a.x - m) + b.y * expf(a.y - m)
             + b.z * expf(a.z - m) + b.w * expf(a.w - m);
    }
    loss[n] = logf(sum) + m - lp;
}

__global__ __launch_bounds__(256) void reduce_kernel(
    const float* __restrict__ loss, float* __restrict__ out)
{
    __shared__ float red[256];
    const int t = threadIdx.x;
    red[t] = loss[t] + loss[t + 256];
    __syncthreads();
    for (int s = 128; s > 0; s >>= 1) {
        if (t < s) red[t] += red[t + s];
        __syncthreads();
    }
    if (t == 0) out[0] = red[0] / (float)Nn;
}

extern "C" void kernel_launch(void* const* d_in, const int* in_sizes, int n_in,
                              void* d_out, int out_size, void* d_ws, size_t ws_size,
                              hipStream_t stream) {
    const float* q      = (const float*)d_in[0];
    const float* k      = (const float*)d_in[1];
    const float* queue  = (const float*)d_in[2];
    // d_in[3] = class_weights — unused by the reference computation
    const int* labels   = (const int*)d_in[4];
    float* out          = (float*)d_out;
    float* ws           = (float*)d_ws;
    float* loss         = ws + 2 * (size_t)Nn * KCW;

    chunk_kernel<<<Cc * NPAIR, 256, 0, stream>>>(q, queue, labels, ws);
    loss_kernel<<<Nn / 64, 64, 0, stream>>>(q, k, ws, loss);
    reduce_kernel<<<1, 256, 0, stream>>>(loss, out);
}

// Round 16
// 39.427 us; speedup vs baseline: 1.1967x; 1.1967x over previous
//
#include <hip/hip_runtime.h>

#define Nn 512
#define Dd 128
#define Kk 2048
#define Cc 100
#define KCW 64          // 64 chunks of 32 cols per class; one wave each
constexpr float INV_T = 1.0f / 0.07f;

// ws layout (floats):
// [0, 32768)         stats_m[n*KCW+kc]
// [32768, 65536)     stats_s[n*KCW+kc]
// [65536, 66048)     per-sample loss

__global__ __launch_bounds__(64) void chunk_kernel(
    const float* __restrict__ q,
    const float* __restrict__ queue, const int* __restrict__ labels,
    float* __restrict__ ws)
{
    const int c  = blockIdx.x >> 6;      // class
    const int kc = blockIdx.x & 63;      // 32-col chunk
    const int l  = threadIdx.x;          // single wave, no barriers anywhere
    const int dg = l >> 3;               // d-group 0..7 (16 rows each)
    const int c4 = l & 7;                // col-group 0..7 (4 cols each)

    __shared__ int s_list[Nn];           // 2 KB; within-wave ordering via lgkmcnt

    // 1) prefetch all 8 label words (oldest in vmcnt queue)
    int lab[8];
    #pragma unroll
    for (int r = 0; r < 8; ++r) lab[r] = labels[l + r * 64];

    // 2) issue the 16 independent V loads (live across the whole block)
    const float* gbase = queue + (size_t)c * Dd * Kk
                       + (size_t)(dg * 16) * Kk + kc * 32 + c4 * 4;
    float4 V[16];
    #pragma unroll
    for (int j = 0; j < 16; ++j)
        V[j] = *reinterpret_cast<const float4*>(gbase + (size_t)j * Kk);

    // 3) in-wave ballot scan: deterministic ordered sample list for class c
    int cnt = 0;
    #pragma unroll
    for (int r = 0; r < 8; ++r) {
        unsigned long long m = __ballot(lab[r] == c);
        if (lab[r] == c) {
            int pos = __popcll(m & ((1ull << l) - 1ull));
            s_list[cnt + pos] = r * 64 + l;
        }
        cnt += __popcll(m);              // wave-uniform
    }
    if (cnt == 0) return;

    float* stats_m = ws;
    float* stats_s = ws + (size_t)Nn * KCW;

    // 4) sample loop, software-pipelined one ahead: q rows read directly from
    //    global (L2-resident; 8 lanes per dg read the same addresses ->
    //    hardware broadcast). Next sample's loads issue before this sample's
    //    latency-bound reduce chain.
    int ncur = s_list[0];
    const float* qr = q + (size_t)ncur * Dd + dg * 16;
    float4 qa = *reinterpret_cast<const float4*>(qr + 0);
    float4 qb = *reinterpret_cast<const float4*>(qr + 4);
    float4 qc = *reinterpret_cast<const float4*>(qr + 8);
    float4 qd = *reinterpret_cast<const float4*>(qr + 12);

    for (int s = 0; s < cnt; ++s) {
        const float4 ra = qa, rb = qb, rc = qc, rd = qd;
        const int nthis = ncur;
        if (s + 1 < cnt) {
            ncur = s_list[s + 1];
            const float* q2 = q + (size_t)ncur * Dd + dg * 16;
            qa = *reinterpret_cast<const float4*>(q2 + 0);
            qb = *reinterpret_cast<const float4*>(q2 + 4);
            qc = *reinterpret_cast<const float4*>(q2 + 8);
            qd = *reinterpret_cast<const float4*>(q2 + 12);
        }

        const float qq[16] = {ra.x, ra.y, ra.z, ra.w, rb.x, rb.y, rb.z, rb.w,
                              rc.x, rc.y, rc.z, rc.w, rd.x, rd.y, rd.z, rd.w};

        float4 a = make_float4(0.f, 0.f, 0.f, 0.f);
        #pragma unroll
        for (int j = 0; j < 16; ++j) {
            a.x = fmaf(qq[j], V[j].x, a.x);
            a.y = fmaf(qq[j], V[j].y, a.y);
            a.z = fmaf(qq[j], V[j].z, a.z);
            a.w = fmaf(qq[j], V[j].w, a.w);
        }

        // d-reduce across dg (lane bits 3..5)
        #pragma unroll
        for (int mask = 8; mask <= 32; mask <<= 1) {
            a.x += __shfl_xor(a.x, mask, 64);
            a.y += __shfl_xor(a.y, mask, 64);
            a.z += __shfl_xor(a.z, mask, 64);
            a.w += __shfl_xor(a.w, mask, 64);
        }
        const float lx = a.x * INV_T, ly = a.y * INV_T;
        const float lz = a.z * INV_T, lw = a.w * INV_T;

        // softmax stats across c4 (lane bits 0..2)
        float mv = fmaxf(fmaxf(lx, ly), fmaxf(lz, lw));
        #pragma unroll
        for (int mask = 1; mask <= 4; mask <<= 1)
            mv = fmaxf(mv, __shfl_xor(mv, mask, 64));
        float ev = expf(lx - mv) + expf(ly - mv) + expf(lz - mv) + expf(lw - mv);
        #pragma unroll
        for (int mask = 1; mask <= 4; mask <<= 1)
            ev += __shfl_xor(ev, mask, 64);

        if (l == 0) {
            stats_m[(size_t)nthis * KCW + kc] = mv;
            stats_s[(size_t)nthis * KCW + kc] = ev;
        }
    }
}

__global__ __launch_bounds__(64) void loss_kernel(
    const float* __restrict__ q, const float* __restrict__ k,
    const float* __restrict__ ws, float* __restrict__ loss)
{
    const int n = blockIdx.x * 64 + threadIdx.x;
    const float* stats_m = ws;
    const float* stats_s = ws + (size_t)Nn * KCW;

    // l_pos = dot(q[n], k[n]) / T
    float lp = 0.f;
    const float4* qv = reinterpret_cast<const float4*>(q + (size_t)n * Dd);
    const float4* kv = reinterpret_cast<const float4*>(k + (size_t)n * Dd);
    #pragma unroll
    for (int j = 0; j < Dd / 4; ++j) {
        float4 a = qv[j], b = kv[j];
        lp = fmaf(a.x, b.x, lp); lp = fmaf(a.y, b.y, lp);
        lp = fmaf(a.z, b.z, lp); lp = fmaf(a.w, b.w, lp);
    }
    lp *= INV_T;

    const float4* mmv = reinterpret_cast<const float4*>(stats_m + (size_t)n * KCW);
    const float4* ssv = reinterpret_cast<const float4*>(stats_s + (size_t)n * KCW);

    float m = lp;
    #pragma unroll
    for (int j = 0; j < KCW / 4; ++j) {
        float4 a = mmv[j];
        m = fmaxf(m, fmaxf(fmaxf(a.x, a.y), fmaxf(a.z, a.w)));
    }
    float sum = expf(lp - m);
    #pragma unroll
    for (int j = 0; j < KCW / 4; ++j) {
        float4 a = mmv[j], b = ssv[j];
        sum += b.x * expf(a.x - m) + b.y * expf(a.y - m)
             + b.z * expf(a.z - m) + b.w * expf(a.w - m);
    }
    loss[n] = logf(sum) + m - lp;
}

__global__ __launch_bounds__(256) void reduce_kernel(
    const float* __restrict__ loss, float* __restrict__ out)
{
    __shared__ float red[256];
    const int t = threadIdx.x;
    red[t] = loss[t] + loss[t + 256];
    __syncthreads();
    for (int s = 128; s > 0; s >>= 1) {
        if (t < s) red[t] += red[t + s];
        __syncthreads();
    }
    if (t == 0) out[0] = red[0] / (float)Nn;
}

extern "C" void kernel_launch(void* const* d_in, const int* in_sizes, int n_in,
                              void* d_out, int out_size, void* d_ws, size_t ws_size,
                              hipStream_t stream) {
    const float* q      = (const float*)d_in[0];
    const float* k      = (const float*)d_in[1];
    const float* queue  = (const float*)d_in[2];
    // d_in[3] = class_weights — unused by the reference computation
    const int* labels   = (const int*)d_in[4];
    float* out          = (float*)d_out;
    float* ws           = (float*)d_ws;
    float* loss         = ws + 2 * (size_t)Nn * KCW;

    chunk_kernel<<<Cc * KCW, 64, 0, stream>>>(q, queue, labels, ws);
    loss_kernel<<<Nn / 64, 64, 0, stream>>>(q, k, ws, loss);
    reduce_kernel<<<1, 256, 0, stream>>>(loss, out);
}